// Round 3
// baseline (391.884 us; speedup 1.0000x reference)
//
#include <hip/hip_runtime.h>

// ---------------------------------------------------------------------------
// WindowAttention fused kernel for MI355X (gfx950). FP32 I/O per reference:
//   x [2048][49][256], mask [64][49][49], qkv_w [256][768], qkv_b [768],
//   proj_w [256][256], proj_b [256], bias_table [169][8], rel_index [2401]i32
//   out [2048][49][256]
// Internals: bf16 MFMA (16x16x32), fp32 accumulate, exp2-domain softmax.
// R3 structure: 4 phases x 2 heads; parallel per-wave dump; per-head proj
// accumulated in persistent registers; 9 barriers/block (was 34).
// ---------------------------------------------------------------------------

typedef __attribute__((ext_vector_type(8))) short v8s;   // 8 x bf16 (4 VGPRs)
typedef __attribute__((ext_vector_type(4))) float v4f;   // MFMA accumulator

__device__ __forceinline__ unsigned short f2bf(float f) {   // RNE f32->bf16
    union { float f; unsigned int i; } v; v.f = f;
    unsigned int x = v.i;
    return (unsigned short)((x + 0x7fffu + ((x >> 16) & 1u)) >> 16);
}

#define NW1 196608              // W1f elements (48 tiles * 8 ksteps * 64 lanes * 8)
#define NW2 65536               // W2f elements (16 tiles * 8 ksteps * 64 lanes * 8)
#define NB1 768                 // B1v elements
#define NCB 1605632             // CBf elements (64*8*49*64), fp32
#define QSCALE_LOG2E 0.25503487f   // (1/sqrt(32)) * log2(e)
#define LOG2E 1.4426950408889634f

// LDS geometry (shorts)
#define QS_H 1960   // 49*40 per head
#define VS_H 2304   // 32*72 per head
#define PS_H 3528   // 49*72 per head (O_h overlays cols 0..31)

// ---------------------------------------------------------------------------
// Preprocessing (unchanged from R2): fragment-linear bf16 weights + fp32 CB.
// ---------------------------------------------------------------------------
__global__ void wattn_preproc(const float* __restrict__ qkv_w,
                              const float* __restrict__ qkv_b,
                              const float* __restrict__ proj_w,
                              const float* __restrict__ bias_table,
                              const float* __restrict__ mask,
                              const int* __restrict__ rel_index,
                              unsigned short* __restrict__ W1f,
                              unsigned short* __restrict__ W2f,
                              float* __restrict__ B1v,
                              float* __restrict__ CBf)
{
    const int idx = blockIdx.x * 256 + threadIdx.x;
    if (idx < NW1) {
        const int j = idx & 7, l = (idx >> 3) & 63, s = (idx >> 9) & 7, T = idx >> 12;
        const int k = s * 32 + (l >> 4) * 8 + j;
        const int n = T * 16 + (l & 15);
        const int hh = n / 96, sub = n % 96;
        const int col = (sub < 32) ? (hh * 32 + sub)
                      : (sub < 64) ? (256 + hh * 32 + (sub - 32))
                                   : (512 + hh * 32 + (sub - 64));
        float v = qkv_w[k * 768 + col];
        if (sub < 32) v *= QSCALE_LOG2E;
        W1f[idx] = f2bf(v);
    } else if (idx < NW1 + NW2) {
        const int t = idx - NW1;
        const int j = t & 7, l = (t >> 3) & 63, s = (t >> 9) & 7, T = t >> 12;
        const int k = s * 32 + (l >> 4) * 8 + j;
        const int n = T * 16 + (l & 15);
        W2f[t] = f2bf(proj_w[k * 256 + n]);
    } else if (idx < NW1 + NW2 + NB1) {
        const int n = idx - NW1 - NW2;
        const int hh = n / 96, sub = n % 96;
        const int col = (sub < 32) ? (hh * 32 + sub)
                      : (sub < 64) ? (256 + hh * 32 + (sub - 32))
                                   : (512 + hh * 32 + (sub - 64));
        float v = qkv_b[col];
        if (sub < 32) v *= QSCALE_LOG2E;
        B1v[n] = v;
    } else {
        const int t = idx - (NW1 + NW2 + NB1);
        if (t < NCB) {
            const int c = t & 63;
            const int rr = t >> 6;
            const int r = rr % 49;
            const int q2 = rr / 49;
            const int hh = q2 & 7;
            const int w = q2 >> 3;
            float v;
            if (c < 49) {
                const int ri = rel_index[r * 49 + c];
                v = (bias_table[ri * 8 + hh] + mask[(w * 49 + r) * 49 + c]) * LOG2E;
            } else {
                v = -1e30f;
            }
            CBf[t] = v;
        }
    }
}

// ---------------------------------------------------------------------------
// Main fused kernel: one block (4 waves) per window; 4 phases x 2 heads.
// ---------------------------------------------------------------------------
__global__ __launch_bounds__(256, 2)
void wattn_main(const float* __restrict__ x,
                const unsigned short* __restrict__ W1f,
                const float* __restrict__ B1v,
                const float* __restrict__ CB,
                const unsigned short* __restrict__ W2f,
                const float* __restrict__ proj_b,
                float* __restrict__ out)
{
    // Total LDS = 25872 + 7840 + 7840 + 9216 + 14112 = 64880 B (2 blocks/CU)
    __shared__ __align__(16) unsigned short xs[49 * 264];   // x bf16, resident
    __shared__ __align__(16) unsigned short qs[2 * QS_H];   // q [tok][d] per head
    __shared__ __align__(16) unsigned short ks[2 * QS_H];   // k [tok][d] per head
    __shared__ __align__(16) unsigned short Vs[2 * VS_H];   // v^T [d][tok], cols 49..63 zero
    __shared__ __align__(16) unsigned short Ps[2 * PS_H];   // P [q][key]; O_h overlays cols 0..31

    const int tid  = threadIdx.x;
    const int wave = tid >> 6;
    const int lane = tid & 63;
    const int quad = lane >> 4;
    const int l15  = lane & 15;
    const int b    = blockIdx.x;
    const int widx = b & 63;
    const float* xw = x + (long)b * 49 * 256;
    const v4f zero4 = {0.0f, 0.0f, 0.0f, 0.0f};

    const int hh01 = wave >> 1;        // local head this wave attends
    const int u0   = (wave & 1) * 3;   // within-head n-tile offset for dump
    const int mb   = (wave & 1) * 2;   // query m-tile base for attention

    // Zero Vs pad cols once (tokens 49..63, both heads); never rewritten.
    for (int i = tid; i < 960; i += 256) {
        const int hd2 = i / 480, rem = i % 480;
        Vs[hd2 * VS_H + (rem / 15) * 72 + 49 + rem % 15] = 0;
    }
    // Stage x -> bf16 LDS once (coalesced float4).
    for (int i = tid; i < 49 * 64; i += 256) {
        const int r = i >> 6, cq = i & 63;
        const float4 v = *reinterpret_cast<const float4*>(xw + r * 256 + cq * 4);
        ushort4 o;
        o.x = f2bf(v.x); o.y = f2bf(v.y); o.z = f2bf(v.z); o.w = f2bf(v.w);
        *reinterpret_cast<ushort4*>(&xs[r * 264 + cq * 4]) = o;
    }
    __syncthreads();

    // A-frag row bases in xs (clamped pad rows)
    int arow[4];
    #pragma unroll
    for (int mt = 0; mt < 4; ++mt) {
        int m = mt * 16 + l15; if (m > 48) m = 48;
        arow[mt] = m * 264 + quad * 8;
    }

    v4f pacc[4][4];   // persistent proj accumulator: nt = wave*4+i, mt
    #pragma unroll
    for (int i = 0; i < 4; ++i)
        #pragma unroll
        for (int mt = 0; mt < 4; ++mt) pacc[i][mt] = zero4;

    unsigned short* qb = qs + hh01 * QS_H;
    unsigned short* kb = ks + hh01 * QS_H;
    unsigned short* Vb = Vs + hh01 * VS_H;
    unsigned short* Pb = Ps + hh01 * PS_H;

    #pragma unroll 1
    for (int p = 0; p < 4; ++p) {
        // ---- QKV GEMM: wave owns 3 n-tiles (W1f read exactly once/block) ----
        v4f acc[3][4];
        #pragma unroll
        for (int i = 0; i < 3; ++i)
            #pragma unroll
            for (int mt = 0; mt < 4; ++mt) acc[i][mt] = zero4;

        const int G0 = p * 12 + wave * 3;
        const unsigned short* bb = W1f + G0 * 4096 + lane * 8;

        #pragma unroll
        for (int s = 0; s < 8; ++s) {
            v8s afr[4];
            #pragma unroll
            for (int mt = 0; mt < 4; ++mt)
                afr[mt] = *reinterpret_cast<const v8s*>(&xs[arow[mt] + s * 32]);
            v8s bfr[3];
            #pragma unroll
            for (int i = 0; i < 3; ++i)
                bfr[i] = *reinterpret_cast<const v8s*>(bb + i * 4096 + s * 512);
            #pragma unroll
            for (int i = 0; i < 3; ++i)
                #pragma unroll
                for (int mt = 0; mt < 4; ++mt)
                    acc[i][mt] = __builtin_amdgcn_mfma_f32_16x16x32_bf16(afr[mt], bfr[i], acc[i][mt], 0, 0, 0);
        }
        #pragma unroll
        for (int i = 0; i < 3; ++i) {
            const float bv = B1v[(G0 + i) * 16 + l15];
            #pragma unroll
            for (int mt = 0; mt < 4; ++mt) {
                acc[i][mt].x += bv; acc[i][mt].y += bv; acc[i][mt].z += bv; acc[i][mt].w += bv;
            }
        }

        // ---- parallel dump: every wave writes its own 3 tiles ----
        #pragma unroll
        for (int i = 0; i < 3; ++i) {
            const int u = u0 + i;   // 0,1=q cols; 2,3=k cols; 4,5=v dims
            #pragma unroll
            for (int mt = 0; mt < 4; ++mt) {
                const int m0 = mt * 16 + quad * 4;
                float vv[4] = {acc[i][mt].x, acc[i][mt].y, acc[i][mt].z, acc[i][mt].w};
                if (u < 2) {
                    const int c = u * 16 + l15;
                    #pragma unroll
                    for (int r = 0; r < 4; ++r)
                        if (m0 + r < 49) qb[(m0 + r) * 40 + c] = f2bf(vv[r]);
                } else if (u < 4) {
                    const int c = (u - 2) * 16 + l15;
                    #pragma unroll
                    for (int r = 0; r < 4; ++r)
                        if (m0 + r < 49) kb[(m0 + r) * 40 + c] = f2bf(vv[r]);
                } else {
                    const int d = (u - 4) * 16 + l15;
                    if (mt < 3) {
                        ushort4 pk;
                        pk.x = f2bf(vv[0]); pk.y = f2bf(vv[1]);
                        pk.z = f2bf(vv[2]); pk.w = f2bf(vv[3]);
                        *reinterpret_cast<ushort4*>(&Vb[d * 72 + m0]) = pk;
                    } else if (quad == 0) {
                        Vb[d * 72 + 48] = f2bf(vv[0]);
                    }
                }
            }
        }
        __syncthreads();   // barrier 1/phase: qkv visible

        const int h = 2 * p + hh01;   // global head this wave attends

        // ---- QK^T: wave owns rows [mb*16, mb*16+32) of its head ----
        v8s aq[2];
        #pragma unroll
        for (int mt2 = 0; mt2 < 2; ++mt2) {
            int row = (mb + mt2) * 16 + l15; if (row > 48) row = 48;
            aq[mt2] = *reinterpret_cast<const v8s*>(&qb[row * 40 + quad * 8]);
        }
        v4f sacc[2][4];
        #pragma unroll
        for (int nt = 0; nt < 4; ++nt) {
            int kr = nt * 16 + l15; if (kr > 48) kr = 48;
            const v8s bk = *reinterpret_cast<const v8s*>(&kb[kr * 40 + quad * 8]);
            #pragma unroll
            for (int mt2 = 0; mt2 < 2; ++mt2)
                sacc[mt2][nt] = __builtin_amdgcn_mfma_f32_16x16x32_bf16(aq[mt2], bk, zero4, 0, 0, 0);
        }

        // ---- softmax (exp2 domain) + P store ----
        const float* cbb = CB + (((long)widx * 8 + h) * 49) * 64;
        #pragma unroll
        for (int mt2 = 0; mt2 < 2; ++mt2) {
            #pragma unroll
            for (int r = 0; r < 4; ++r) {
                const int m = (mb + mt2) * 16 + quad * 4 + r;
                const int mc = m > 48 ? 48 : m;
                float s0 = sacc[mt2][0][r] + cbb[mc * 64 + l15];
                float s1 = sacc[mt2][1][r] + cbb[mc * 64 + 16 + l15];
                float s2 = sacc[mt2][2][r] + cbb[mc * 64 + 32 + l15];
                float s3 = sacc[mt2][3][r] + cbb[mc * 64 + 48 + l15];
                float mx = fmaxf(fmaxf(s0, s1), fmaxf(s2, s3));
                #pragma unroll
                for (int off = 1; off < 16; off <<= 1) mx = fmaxf(mx, __shfl_xor(mx, off, 16));
                const float e0 = __builtin_exp2f(s0 - mx);
                const float e1 = __builtin_exp2f(s1 - mx);
                const float e2 = __builtin_exp2f(s2 - mx);
                const float e3 = __builtin_exp2f(s3 - mx);
                float sm = (e0 + e1) + (e2 + e3);
                #pragma unroll
                for (int off = 1; off < 16; off <<= 1) sm += __shfl_xor(sm, off, 16);
                const float rs = __builtin_amdgcn_rcpf(sm);
                if (m < 49) {
                    Pb[m * 72 + l15]      = f2bf(e0 * rs);
                    Pb[m * 72 + 16 + l15] = f2bf(e1 * rs);
                    Pb[m * 72 + 32 + l15] = f2bf(e2 * rs);
                    Pb[m * 72 + 48 + l15] = f2bf(e3 * rs);
                }
            }
        }
        // no barrier: this wave reads back only its own P rows

        // ---- P @ V ----
        int prow[2];
        #pragma unroll
        for (int mt2 = 0; mt2 < 2; ++mt2) {
            int row = (mb + mt2) * 16 + l15; if (row > 48) row = 48;
            prow[mt2] = row * 72;
        }
        v4f oacc[2][2] = {{zero4, zero4}, {zero4, zero4}};
        #pragma unroll
        for (int kt = 0; kt < 2; ++kt) {
            v8s ap[2];
            #pragma unroll
            for (int mt2 = 0; mt2 < 2; ++mt2)
                ap[mt2] = *reinterpret_cast<const v8s*>(&Pb[prow[mt2] + kt * 32 + quad * 8]);
            #pragma unroll
            for (int n2 = 0; n2 < 2; ++n2) {
                const v8s bv = *reinterpret_cast<const v8s*>(&Vb[(n2 * 16 + l15) * 72 + kt * 32 + quad * 8]);
                #pragma unroll
                for (int mt2 = 0; mt2 < 2; ++mt2)
                    oacc[mt2][n2] = __builtin_amdgcn_mfma_f32_16x16x32_bf16(ap[mt2], bv, oacc[mt2][n2], 0, 0, 0);
            }
        }
        // O_h overlays P cols 0..31 (own rows only; PV reads of those rows done)
        #pragma unroll
        for (int mt2 = 0; mt2 < 2; ++mt2)
            #pragma unroll
            for (int n2 = 0; n2 < 2; ++n2)
                #pragma unroll
                for (int r = 0; r < 4; ++r) {
                    const int m = (mb + mt2) * 16 + quad * 4 + r;
                    if (m < 49) Pb[m * 72 + n2 * 16 + l15] = f2bf(oacc[mt2][n2][r]);
                }
        __syncthreads();   // barrier 2/phase: O_h visible to all waves

        // ---- per-head projection contribution (K=32 = 1 kstep; s index = head) ----
        #pragma unroll
        for (int hh = 0; hh < 2; ++hh) {
            const unsigned short* Ob = Ps + hh * PS_H;
            v8s oaf[4];
            #pragma unroll
            for (int mt = 0; mt < 4; ++mt) {
                int row = mt * 16 + l15; if (row > 48) row = 48;
                oaf[mt] = *reinterpret_cast<const v8s*>(&Ob[row * 72 + quad * 8]);
            }
            const int hg = 2 * p + hh;
            #pragma unroll
            for (int i = 0; i < 4; ++i) {
                const v8s bfp = *reinterpret_cast<const v8s*>(W2f + (wave * 4 + i) * 4096 + hg * 512 + lane * 8);
                #pragma unroll
                for (int mt = 0; mt < 4; ++mt)
                    pacc[i][mt] = __builtin_amdgcn_mfma_f32_16x16x32_bf16(oaf[mt], bfp, pacc[i][mt], 0, 0, 0);
            }
        }
        // next phase's dump waits at its own post-dump barrier, which is after
        // every wave's proj reads here -> no extra barrier needed
    }

    // ---- epilogue: wave owns output cols [wave*64, wave*64+64) ----
    #pragma unroll
    for (int i = 0; i < 4; ++i) {
        const int c = (wave * 4 + i) * 16 + l15;
        const float pb = proj_b[c];
        #pragma unroll
        for (int mt = 0; mt < 4; ++mt) {
            #pragma unroll
            for (int r = 0; r < 4; ++r) {
                const int m = mt * 16 + quad * 4 + r;
                if (m < 49) out[((long)b * 49 + m) * 256 + c] = pacc[i][mt][r] + pb;
            }
        }
    }
}

// ---------------------------------------------------------------------------
extern "C" void kernel_launch(void* const* d_in, const int* in_sizes, int n_in,
                              void* d_out, int out_size, void* d_ws, size_t ws_size,
                              hipStream_t stream)
{
    const float* x          = (const float*)d_in[0];
    const float* mask       = (const float*)d_in[1];
    const float* qkv_w      = (const float*)d_in[2];
    const float* qkv_b      = (const float*)d_in[3];
    const float* proj_w     = (const float*)d_in[4];
    const float* proj_b     = (const float*)d_in[5];
    const float* bias_table = (const float*)d_in[6];
    const int*   rel_index  = (const int*)d_in[7];
    float* out = (float*)d_out;

    char* ws = (char*)d_ws;
    unsigned short* W1f = (unsigned short*)(ws);             // 393216 B
    unsigned short* W2f = (unsigned short*)(ws + 393216);    // 131072 B
    float*          B1v = (float*)(ws + 524288);             //   3072 B
    float*          CBf = (float*)(ws + 527360);             // 6422528 B (total ~6.95 MB)

    // 196608 + 65536 + 768 + 1605632 = 1868544 = 7299 * 256 exactly
    wattn_preproc<<<7299, 256, 0, stream>>>(qkv_w, qkv_b, proj_w, bias_table, mask,
                                            rel_index, W1f, W2f, B1v, CBf);
    wattn_main<<<2048, 256, 0, stream>>>(x, W1f, B1v, CBf, W2f, proj_b, out);
}